// Round 1
// baseline (1983.841 us; speedup 1.0000x reference)
//
#include <hip/hip_runtime.h>
#include <math.h>

#define SS 128
#define BB 32
#define VV 32000
#define EE 32
#define HH 16
#define NVT 5
#define VT (VV / NVT)        // 6400, 6400/256 = 25 exact iters
#define RPB 16               // rows per block in vocab kernels
#define NROWS (SS*BB)        // 4096
#define NRT (NROWS / RPB)    // 256

// ------------------------------------------------------------------
// Kernel A: input projection  xp[dir][t][b][j] = b_dir[j] + emb[tok[t,b],:] . W_dir[j, 0:32]
// ------------------------------------------------------------------
__global__ __launch_bounds__(256) void k_xproj(
    const int* __restrict__ tok, const float* __restrict__ emb,
    const float* __restrict__ Wlr, const float* __restrict__ blr,
    const float* __restrict__ Wrl, const float* __restrict__ brl,
    float* __restrict__ xp) {
  int g = blockIdx.x * 256 + threadIdx.x;     // 0 .. 131071
  int dir = g >> 16;
  int rem = g & 65535;                        // t*512 + b*16 + j
  int t = rem >> 9;
  int b = (rem >> 4) & 31;
  int j = rem & 15;
  const float* W  = dir ? Wrl : Wlr;
  const float* bv = dir ? brl : blr;
  int tk = tok[t*BB + b];
  const float* er = emb + tk*EE;
  const float* wr = W + j*(EE+HH);
  float acc = bv[j];
  #pragma unroll
  for (int k = 0; k < EE; ++k) acc += er[k] * wr[k];
  xp[g] = acc;
}

// ------------------------------------------------------------------
// Kernel B: the two recurrences (dir = blockIdx.x), h part only.
// Writes combined[t][b][0:16] = hLR[t], combined[t][b][16:32] = hRL[S-1-t]
// ------------------------------------------------------------------
__global__ __launch_bounds__(512) void k_rnn(
    const float* __restrict__ xp,
    const float* __restrict__ h0lr, const float* __restrict__ h0rl,
    const float* __restrict__ Wlr, const float* __restrict__ Wrl,
    float* __restrict__ comb) {
  int dir = blockIdx.x;
  int tid = threadIdx.x;        // 0..511
  int b = tid >> 4, j = tid & 15;
  const float* W  = dir ? Wrl : Wlr;
  const float* h0 = dir ? h0rl : h0lr;
  const float* x  = xp + dir * (SS*BB*HH);
  float wh[HH];
  #pragma unroll
  for (int k = 0; k < HH; ++k) wh[k] = W[j*(EE+HH) + EE + k];
  __shared__ float hs[2][BB*HH];
  float h = h0[b*HH + j];
  hs[0][tid] = h;
  if (dir == 0) comb[0*(BB*2*HH) + b*(2*HH) + j] = h;
  else          comb[(SS-1)*(BB*2*HH) + b*(2*HH) + HH + j] = h;
  __syncthreads();
  int p = 0;
  for (int t = 1; t < SS; ++t) {
    float acc = (dir == 0) ? x[(t-1)*(BB*HH) + tid] : x[(SS - t)*(BB*HH) + tid];
    #pragma unroll
    for (int k = 0; k < HH; ++k) acc += wh[k] * hs[p][b*HH + k];
    float hn = tanhf(acc);
    hs[p^1][tid] = hn;
    if (dir == 0) comb[t*(BB*2*HH) + b*(2*HH) + j] = hn;
    else          comb[(SS-1-t)*(BB*2*HH) + b*(2*HH) + HH + j] = hn;
    __syncthreads();
    p ^= 1;
  }
}

// ------------------------------------------------------------------
// Kernel C: per (row-tile, vocab-tile) partial sum of exp(logit).
// No max subtraction: |logit| <= sum|W_ho row| ~ 11, exp safe in fp32.
// comb rows are BLOCK-UNIFORM -> compiler emits s_load + FMA w/ SGPR operand.
// ------------------------------------------------------------------
__global__ __launch_bounds__(256) void k_sumexp(
    const float* __restrict__ comb, const float* __restrict__ Who,
    const float* __restrict__ bho, float* __restrict__ part) {
  int rt = blockIdx.x / NVT;
  int vt = blockIdx.x % NVT;
  int r0 = rt * RPB;
  int v0 = vt * VT;
  const float* c = comb + r0 * (2*HH);
  float s[RPB];
  #pragma unroll
  for (int r = 0; r < RPB; ++r) s[r] = 0.f;
  for (int v = v0 + threadIdx.x; v < v0 + VT; v += 256) {
    const float4* wr = (const float4*)(Who + (size_t)v*(2*HH));
    float w[2*HH];
    #pragma unroll
    for (int q = 0; q < 8; ++q) {
      float4 t4 = wr[q];
      w[4*q+0]=t4.x; w[4*q+1]=t4.y; w[4*q+2]=t4.z; w[4*q+3]=t4.w;
    }
    float bh = bho[v];
    #pragma unroll
    for (int r = 0; r < RPB; ++r) {
      float l = bh;
      #pragma unroll
      for (int k = 0; k < 2*HH; ++k) l += c[r*(2*HH) + k] * w[k];
      s[r] += __expf(l);
    }
  }
  // wave-level reduce, then cross-wave via LDS
  #pragma unroll
  for (int r = 0; r < RPB; ++r) {
    float vv = s[r];
    #pragma unroll
    for (int o = 32; o > 0; o >>= 1) vv += __shfl_xor(vv, o);
    s[r] = vv;
  }
  __shared__ float red[4][RPB];
  int wid = threadIdx.x >> 6, lane = threadIdx.x & 63;
  if (lane == 0) {
    #pragma unroll
    for (int r = 0; r < RPB; ++r) red[wid][r] = s[r];
  }
  __syncthreads();
  if (threadIdx.x < RPB) {
    float t = red[0][threadIdx.x] + red[1][threadIdx.x] + red[2][threadIdx.x] + red[3][threadIdx.x];
    part[(r0 + threadIdx.x)*NVT + vt] = t;
  }
}

// ------------------------------------------------------------------
// Kernel D: merge vocab-tile partials -> L[r] = log(sum_exp)
// ------------------------------------------------------------------
__global__ __launch_bounds__(256) void k_merge(
    const float* __restrict__ part, float* __restrict__ L) {
  int r = blockIdx.x * 256 + threadIdx.x;  // 4096 total
  float s = 0.f;
  #pragma unroll
  for (int i = 0; i < NVT; ++i) s += part[r*NVT + i];
  L[r] = logf(s);
}

// ------------------------------------------------------------------
// Kernel E: recompute logits, write out = logit - L[r]
// ------------------------------------------------------------------
__global__ __launch_bounds__(256) void k_out(
    const float* __restrict__ comb, const float* __restrict__ Who,
    const float* __restrict__ bho, const float* __restrict__ L,
    float* __restrict__ out) {
  int rt = blockIdx.x / NVT;
  int vt = blockIdx.x % NVT;
  int r0 = rt * RPB;
  int v0 = vt * VT;
  const float* c = comb + r0 * (2*HH);
  float Lr[RPB];
  #pragma unroll
  for (int r = 0; r < RPB; ++r) Lr[r] = L[r0 + r];
  for (int v = v0 + threadIdx.x; v < v0 + VT; v += 256) {
    const float4* wr = (const float4*)(Who + (size_t)v*(2*HH));
    float w[2*HH];
    #pragma unroll
    for (int q = 0; q < 8; ++q) {
      float4 t4 = wr[q];
      w[4*q+0]=t4.x; w[4*q+1]=t4.y; w[4*q+2]=t4.z; w[4*q+3]=t4.w;
    }
    float bh = bho[v];
    #pragma unroll
    for (int r = 0; r < RPB; ++r) {
      float l = bh;
      #pragma unroll
      for (int k = 0; k < 2*HH; ++k) l += c[r*(2*HH) + k] * w[k];
      out[(size_t)(r0 + r)*VV + v] = l - Lr[r];
    }
  }
}

// ------------------------------------------------------------------
extern "C" void kernel_launch(void* const* d_in, const int* in_sizes, int n_in,
                              void* d_out, int out_size, void* d_ws, size_t ws_size,
                              hipStream_t stream) {
  const int*   tok  = (const int*)d_in[0];
  const float* h0lr = (const float*)d_in[1];
  const float* h0rl = (const float*)d_in[2];
  const float* emb  = (const float*)d_in[3];
  const float* Wlr  = (const float*)d_in[4];
  const float* blr  = (const float*)d_in[5];
  const float* Wrl  = (const float*)d_in[6];
  const float* brl  = (const float*)d_in[7];
  const float* Who  = (const float*)d_in[8];
  const float* bho  = (const float*)d_in[9];
  float* out = (float*)d_out;
  float* ws  = (float*)d_ws;

  float* xp   = ws;                 // 2*128*32*16 = 131072 floats
  float* comb = ws + 131072;        // 128*32*32   = 131072 floats
  float* part = ws + 262144;        // 4096*5      =  20480 floats
  float* L    = ws + 282624;        // 4096 floats

  hipLaunchKernelGGL(k_xproj, dim3(512), dim3(256), 0, stream,
                     tok, emb, Wlr, blr, Wrl, brl, xp);
  hipLaunchKernelGGL(k_rnn, dim3(2), dim3(512), 0, stream,
                     xp, h0lr, h0rl, Wlr, Wrl, comb);
  hipLaunchKernelGGL(k_sumexp, dim3(NRT*NVT), dim3(256), 0, stream,
                     comb, Who, bho, part);
  hipLaunchKernelGGL(k_merge, dim3(16), dim3(256), 0, stream, part, L);
  hipLaunchKernelGGL(k_out, dim3(NRT*NVT), dim3(256), 0, stream,
                     comb, Who, bho, L, out);
}

// Round 2
// 286.117 us; speedup vs baseline: 6.9337x; 6.9337x over previous
//
#include <hip/hip_runtime.h>
#include <hip/hip_bf16.h>
#include <math.h>

#define SS 128
#define BB 32
#define VV 32000
#define EE 32
#define HH 16
#define KK 32                 // 2*HH = GEMM K
#define NROWS (SS*BB)         // 4096
#define NVT16 (VV/16)         // 2000 vocab tiles of 16

// sum-exp pass: each wave = 8 row-tiles (128 rows) x one vocab slice
#define SE_MT 8
#define SE_RG (NROWS/(SE_MT*16))   // 32 rowgroups
#define SE_NV 80                   // vocab slices
#define SE_VT (NVT16/SE_NV)        // 25 tiles per slice

// write pass: each wave = 4 row-tiles (64 rows) x one vocab slice
#define WR_MT 4
#define WR_RG (NROWS/(WR_MT*16))   // 64 rowgroups
#define WR_NV 50
#define WR_VT (NVT16/WR_NV)        // 40 tiles per slice

typedef __attribute__((ext_vector_type(4))) float f32x4;
typedef __attribute__((ext_vector_type(8))) short bf16x8;
typedef __attribute__((ext_vector_type(4))) short s16x4;

// ------------------------------------------------------------------
// A: input projection xp[dir][t][b][j] = b[j] + emb[tok[t,b],:] . W[j,0:32]
// ------------------------------------------------------------------
__global__ __launch_bounds__(256) void k_xproj(
    const int* __restrict__ tok, const float* __restrict__ emb,
    const float* __restrict__ Wlr, const float* __restrict__ blr,
    const float* __restrict__ Wrl, const float* __restrict__ brl,
    float* __restrict__ xp) {
  int g = blockIdx.x * 256 + threadIdx.x;
  int dir = g >> 16;
  int rem = g & 65535;
  int t = rem >> 9;
  int b = (rem >> 4) & 31;
  int j = rem & 15;
  const float* W  = dir ? Wrl : Wlr;
  const float* bv = dir ? brl : blr;
  int tk = tok[t*BB + b];
  const float* er = emb + tk*EE;
  const float* wr = W + j*(EE+HH);
  float acc = bv[j];
  #pragma unroll
  for (int k = 0; k < EE; ++k) acc += er[k] * wr[k];
  xp[g] = acc;
}

// ------------------------------------------------------------------
// B: the two recurrences (dir = blockIdx.x), writes combined fp32
// ------------------------------------------------------------------
__global__ __launch_bounds__(512) void k_rnn(
    const float* __restrict__ xp,
    const float* __restrict__ h0lr, const float* __restrict__ h0rl,
    const float* __restrict__ Wlr, const float* __restrict__ Wrl,
    float* __restrict__ comb) {
  int dir = blockIdx.x;
  int tid = threadIdx.x;
  int b = tid >> 4, j = tid & 15;
  const float* W  = dir ? Wrl : Wlr;
  const float* h0 = dir ? h0rl : h0lr;
  const float* x  = xp + dir * (SS*BB*HH);
  float wh[HH];
  #pragma unroll
  for (int k = 0; k < HH; ++k) wh[k] = W[j*(EE+HH) + EE + k];
  __shared__ float hs[2][BB*HH];
  float h = h0[b*HH + j];
  hs[0][tid] = h;
  if (dir == 0) comb[0*(BB*2*HH) + b*(2*HH) + j] = h;
  else          comb[(SS-1)*(BB*2*HH) + b*(2*HH) + HH + j] = h;
  __syncthreads();
  int p = 0;
  for (int t = 1; t < SS; ++t) {
    float acc = (dir == 0) ? x[(t-1)*(BB*HH) + tid] : x[(SS - t)*(BB*HH) + tid];
    #pragma unroll
    for (int k = 0; k < HH; ++k) acc += wh[k] * hs[p][b*HH + k];
    float hn = tanhf(acc);
    hs[p^1][tid] = hn;
    if (dir == 0) comb[t*(BB*2*HH) + b*(2*HH) + j] = hn;
    else          comb[(SS-1-t)*(BB*2*HH) + b*(2*HH) + HH + j] = hn;
    __syncthreads();
    p ^= 1;
  }
}

// ------------------------------------------------------------------
// fp32 -> bf16 convert (n4 = count of float4 groups)
// ------------------------------------------------------------------
__global__ __launch_bounds__(256) void k_cvt(
    const float* __restrict__ src, __hip_bfloat16* __restrict__ dst, int n4) {
  int i = blockIdx.x * 256 + threadIdx.x;
  if (i >= n4) return;
  f32x4 v = ((const f32x4*)src)[i];
  s16x4 o;
  #pragma unroll
  for (int q = 0; q < 4; ++q) {
    __hip_bfloat16 h = __float2bfloat16(v[q]);
    o[q] = *reinterpret_cast<short*>(&h);
  }
  ((s16x4*)dst)[i] = o;
}

// ------------------------------------------------------------------
// C: sum-exp via MFMA. A = W_ho tile (16 vocab x 32), B = comb row-tiles.
// D layout: col(l&15)=comb row, row((l>>4)*4+j)=vocab. C-in = bho.
// ------------------------------------------------------------------
__global__ __launch_bounds__(256) void k_sumexp(
    const __hip_bfloat16* __restrict__ cb, const __hip_bfloat16* __restrict__ wb,
    const float* __restrict__ bho, float* __restrict__ part) {
  int w = blockIdx.x * 4 + (threadIdx.x >> 6);
  int lane = threadIdx.x & 63;
  int rg = w / SE_NV, sl = w % SE_NV;
  int c0 = rg * (SE_MT*16);
  int v0 = sl * (SE_VT*16);
  int g = lane >> 4, c = lane & 15;
  bf16x8 bfr[SE_MT];
  #pragma unroll
  for (int m = 0; m < SE_MT; ++m)
    bfr[m] = *(const bf16x8*)(cb + (size_t)(c0 + m*16 + c)*KK + g*8);
  float s[SE_MT];
  #pragma unroll
  for (int m = 0; m < SE_MT; ++m) s[m] = 0.f;
  for (int t = 0; t < SE_VT; ++t) {
    int v = v0 + t*16;
    bf16x8 af = *(const bf16x8*)(wb + (size_t)(v + c)*KK + g*8);
    f32x4 bh = *(const f32x4*)(bho + v + g*4);
    #pragma unroll
    for (int m = 0; m < SE_MT; ++m) {
      f32x4 d = __builtin_amdgcn_mfma_f32_16x16x32_bf16(af, bfr[m], bh, 0, 0, 0);
      s[m] += __expf(d[0]) + __expf(d[1]) + __expf(d[2]) + __expf(d[3]);
    }
  }
  #pragma unroll
  for (int m = 0; m < SE_MT; ++m) {
    float v = s[m];
    v += __shfl_xor(v, 16);
    v += __shfl_xor(v, 32);
    s[m] = v;
  }
  if (lane < 16) {
    #pragma unroll
    for (int m = 0; m < SE_MT; ++m)
      part[(size_t)(c0 + m*16 + lane)*SE_NV + sl] = s[m];
  }
}

// ------------------------------------------------------------------
// D: merge partials -> L[r] = log(sum)
// ------------------------------------------------------------------
__global__ __launch_bounds__(256) void k_merge(
    const float* __restrict__ part, float* __restrict__ L) {
  int r = blockIdx.x * 256 + threadIdx.x;
  float s = 0.f;
  #pragma unroll
  for (int i = 0; i < SE_NV; ++i) s += part[(size_t)r*SE_NV + i];
  L[r] = logf(s);
}

// ------------------------------------------------------------------
// E: write pass. C-in = bho - L (fused), D stored as float4 (4 consecutive v).
// ------------------------------------------------------------------
__global__ __launch_bounds__(256) void k_write(
    const __hip_bfloat16* __restrict__ cb, const __hip_bfloat16* __restrict__ wb,
    const float* __restrict__ bho, const float* __restrict__ L,
    float* __restrict__ out) {
  int w = blockIdx.x * 4 + (threadIdx.x >> 6);
  int lane = threadIdx.x & 63;
  int rg = w / WR_NV, sl = w % WR_NV;
  int c0 = rg * (WR_MT*16);
  int v0 = sl * (WR_VT*16);
  int g = lane >> 4, c = lane & 15;
  bf16x8 bfr[WR_MT];
  float Lr[WR_MT];
  #pragma unroll
  for (int m = 0; m < WR_MT; ++m) {
    bfr[m] = *(const bf16x8*)(cb + (size_t)(c0 + m*16 + c)*KK + g*8);
    Lr[m] = L[c0 + m*16 + c];
  }
  for (int t = 0; t < WR_VT; ++t) {
    int v = v0 + t*16;
    bf16x8 af = *(const bf16x8*)(wb + (size_t)(v + c)*KK + g*8);
    f32x4 bh = *(const f32x4*)(bho + v + g*4);
    #pragma unroll
    for (int m = 0; m < WR_MT; ++m) {
      f32x4 cin = bh - Lr[m];
      f32x4 d = __builtin_amdgcn_mfma_f32_16x16x32_bf16(af, bfr[m], cin, 0, 0, 0);
      *(f32x4*)(out + (size_t)(c0 + m*16 + c)*VV + v + g*4) = d;
    }
  }
}

// ------------------------------------------------------------------
extern "C" void kernel_launch(void* const* d_in, const int* in_sizes, int n_in,
                              void* d_out, int out_size, void* d_ws, size_t ws_size,
                              hipStream_t stream) {
  const int*   tok  = (const int*)d_in[0];
  const float* h0lr = (const float*)d_in[1];
  const float* h0rl = (const float*)d_in[2];
  const float* emb  = (const float*)d_in[3];
  const float* Wlr  = (const float*)d_in[4];
  const float* blr  = (const float*)d_in[5];
  const float* Wrl  = (const float*)d_in[6];
  const float* brl  = (const float*)d_in[7];
  const float* Who  = (const float*)d_in[8];
  const float* bho  = (const float*)d_in[9];
  float* out = (float*)d_out;
  float* ws  = (float*)d_ws;

  float* xp   = ws;                       // 131072 floats
  float* comb = ws + 131072;              // 131072 floats
  float* part = ws + 262144;              // 4096*80 = 327680 floats
  float* L    = ws + 589824;              // 4096 floats
  __hip_bfloat16* comb_bf = (__hip_bfloat16*)(ws + 593920);   // 131072 bf16
  __hip_bfloat16* who_bf  = (__hip_bfloat16*)(ws + 659456);   // 1024000 bf16

  // convert W_ho -> bf16 (independent of RNN chain)
  hipLaunchKernelGGL(k_cvt, dim3((VV*KK/4 + 255)/256), dim3(256), 0, stream,
                     Who, who_bf, VV*KK/4);
  hipLaunchKernelGGL(k_xproj, dim3(512), dim3(256), 0, stream,
                     tok, emb, Wlr, blr, Wrl, brl, xp);
  hipLaunchKernelGGL(k_rnn, dim3(2), dim3(512), 0, stream,
                     xp, h0lr, h0rl, Wlr, Wrl, comb);
  hipLaunchKernelGGL(k_cvt, dim3((NROWS*KK/4 + 255)/256), dim3(256), 0, stream,
                     comb, comb_bf, NROWS*KK/4);
  hipLaunchKernelGGL(k_sumexp, dim3(SE_RG*SE_NV/4), dim3(256), 0, stream,
                     comb_bf, who_bf, bho, part);
  hipLaunchKernelGGL(k_merge, dim3(NROWS/256), dim3(256), 0, stream, part, L);
  hipLaunchKernelGGL(k_write, dim3(WR_RG*WR_NV/4), dim3(256), 0, stream,
                     comb_bf, who_bf, bho, L, out);
}

// Round 3
// 283.534 us; speedup vs baseline: 6.9968x; 1.0091x over previous
//
#include <hip/hip_runtime.h>
#include <hip/hip_bf16.h>
#include <math.h>

#define SS 128
#define BB 32
#define VV 32000
#define EE 32
#define HH 16
#define KK 32                 // 2*HH = GEMM K
#define NROWS (SS*BB)         // 4096
#define NVT16 (VV/16)         // 2000 vocab tiles of 16

// sum-exp pass: each wave = 8 row-tiles (128 rows) x one vocab slice
#define SE_MT 8
#define SE_RG (NROWS/(SE_MT*16))   // 32 rowgroups
#define SE_NV 80                   // vocab slices
#define SE_VT (NVT16/SE_NV)        // 25 tiles per slice

// write pass: each wave = 4 row-tiles (64 rows) x one vocab slice
#define WR_MT 4
#define WR_RG (NROWS/(WR_MT*16))   // 64 rowgroups
#define WR_NV 50
#define WR_VT (NVT16/WR_NV)        // 40 tiles per slice

typedef __attribute__((ext_vector_type(4))) float f32x4;
typedef __attribute__((ext_vector_type(8))) short bf16x8;
typedef __attribute__((ext_vector_type(4))) short s16x4;

// ------------------------------------------------------------------
// A: input projection xp[dir][t][b][j] = b[j] + emb[tok[t,b],:] . W[j,0:32]
// ------------------------------------------------------------------
__global__ __launch_bounds__(256) void k_xproj(
    const int* __restrict__ tok, const float* __restrict__ emb,
    const float* __restrict__ Wlr, const float* __restrict__ blr,
    const float* __restrict__ Wrl, const float* __restrict__ brl,
    float* __restrict__ xp) {
  int g = blockIdx.x * 256 + threadIdx.x;
  int dir = g >> 16;
  int rem = g & 65535;
  int t = rem >> 9;
  int b = (rem >> 4) & 31;
  int j = rem & 15;
  const float* W  = dir ? Wrl : Wlr;
  const float* bv = dir ? brl : blr;
  int tk = tok[t*BB + b];
  const float* er = emb + tk*EE;
  const float* wr = W + j*(EE+HH);
  float acc = bv[j];
  #pragma unroll
  for (int k = 0; k < EE; ++k) acc += er[k] * wr[k];
  xp[g] = acc;
}

// ------------------------------------------------------------------
// B: fused recurrence (dir = blockIdx.x), barrier-free: each wave owns
// 4 independent batches; cross-lane h via __shfl within 16-lane groups.
// Writes comb directly in bf16.
// ------------------------------------------------------------------
__global__ __launch_bounds__(512) void k_rnn_fused(
    const float* __restrict__ xp,
    const float* __restrict__ h0lr, const float* __restrict__ h0rl,
    const float* __restrict__ Wlr, const float* __restrict__ Wrl,
    __hip_bfloat16* __restrict__ comb_bf) {
  int dir = blockIdx.x;
  int tid = threadIdx.x;        // 0..511
  int lane = tid & 63;
  int b = tid >> 4;             // 0..31 (batch)
  int j = tid & 15;             // hidden index
  const float* W  = dir ? Wrl : Wlr;
  const float* h0 = dir ? h0rl : h0lr;
  float wh[HH];
  #pragma unroll
  for (int k = 0; k < HH; ++k) wh[k] = W[j*(EE+HH) + EE + k];
  const float* x = xp + dir * (SS*BB*HH);
  float h = h0[b*HH + j];
  if (dir == 0) comb_bf[0*(BB*KK) + b*KK + j] = __float2bfloat16(h);
  else          comb_bf[(SS-1)*(BB*KK) + b*KK + HH + j] = __float2bfloat16(h);
  int xoff  = dir ? ((SS-1)*BB*HH + tid) : tid;
  int xstep = dir ? -(BB*HH) : (BB*HH);
  float xcur = x[xoff];
  int base = lane & 48;
  for (int t = 1; t < SS; ++t) {
    float xnext = (t < SS-1) ? x[xoff + xstep] : 0.f;
    xoff += xstep;
    float acc = xcur;
    #pragma unroll
    for (int k = 0; k < HH; ++k)
      acc += wh[k] * __shfl(h, base | k);
    float e = __expf(2.f * acc);
    h = 1.f - 2.f / (e + 1.f);          // tanh(acc)
    int ci = dir ? ((SS-1-t)*(BB*KK) + b*KK + HH + j)
                 : (t*(BB*KK) + b*KK + j);
    comb_bf[ci] = __float2bfloat16(h);
    xcur = xnext;
  }
}

// ------------------------------------------------------------------
// fp32 -> bf16 convert (for W_ho)
// ------------------------------------------------------------------
__global__ __launch_bounds__(256) void k_cvt(
    const float* __restrict__ src, __hip_bfloat16* __restrict__ dst, int n4) {
  int i = blockIdx.x * 256 + threadIdx.x;
  if (i >= n4) return;
  f32x4 v = ((const f32x4*)src)[i];
  s16x4 o;
  #pragma unroll
  for (int q = 0; q < 4; ++q) {
    __hip_bfloat16 h = __float2bfloat16(v[q]);
    o[q] = *reinterpret_cast<short*>(&h);
  }
  ((s16x4*)dst)[i] = o;
}

// ------------------------------------------------------------------
// C: sum-exp via MFMA. A = W_ho tile (16 vocab x 32), B = comb row-tiles.
// D layout: col(l&15)=comb row, row((l>>4)*4+j)=vocab. C-in = bho.
// ------------------------------------------------------------------
__global__ __launch_bounds__(256) void k_sumexp(
    const __hip_bfloat16* __restrict__ cb, const __hip_bfloat16* __restrict__ wb,
    const float* __restrict__ bho, float* __restrict__ part) {
  int w = blockIdx.x * 4 + (threadIdx.x >> 6);
  int lane = threadIdx.x & 63;
  int rg = w / SE_NV, sl = w % SE_NV;
  int c0 = rg * (SE_MT*16);
  int v0 = sl * (SE_VT*16);
  int g = lane >> 4, c = lane & 15;
  bf16x8 bfr[SE_MT];
  #pragma unroll
  for (int m = 0; m < SE_MT; ++m)
    bfr[m] = *(const bf16x8*)(cb + (size_t)(c0 + m*16 + c)*KK + g*8);
  float s[SE_MT];
  #pragma unroll
  for (int m = 0; m < SE_MT; ++m) s[m] = 0.f;
  for (int t = 0; t < SE_VT; ++t) {
    int v = v0 + t*16;
    bf16x8 af = *(const bf16x8*)(wb + (size_t)(v + c)*KK + g*8);
    f32x4 bh = *(const f32x4*)(bho + v + g*4);
    #pragma unroll
    for (int m = 0; m < SE_MT; ++m) {
      f32x4 d = __builtin_amdgcn_mfma_f32_16x16x32_bf16(af, bfr[m], bh, 0, 0, 0);
      s[m] += __expf(d[0]) + __expf(d[1]) + __expf(d[2]) + __expf(d[3]);
    }
  }
  #pragma unroll
  for (int m = 0; m < SE_MT; ++m) {
    float v = s[m];
    v += __shfl_xor(v, 16);
    v += __shfl_xor(v, 32);
    s[m] = v;
  }
  if (lane < 16) {
    #pragma unroll
    for (int m = 0; m < SE_MT; ++m)
      part[(size_t)(c0 + m*16 + lane)*SE_NV + sl] = s[m];
  }
}

// ------------------------------------------------------------------
// D: merge partials -> L[r] = log(sum)
// ------------------------------------------------------------------
__global__ __launch_bounds__(256) void k_merge(
    const float* __restrict__ part, float* __restrict__ L) {
  int r = blockIdx.x * 256 + threadIdx.x;
  float s = 0.f;
  #pragma unroll
  for (int i = 0; i < SE_NV; ++i) s += part[(size_t)r*SE_NV + i];
  L[r] = logf(s);
}

// ------------------------------------------------------------------
// E: write pass. C-in = bho - L (fused). Non-temporal float4 stores:
// keeps who_bf L2-resident, streams the 524 MB past L2.
// ------------------------------------------------------------------
__global__ __launch_bounds__(256) void k_write(
    const __hip_bfloat16* __restrict__ cb, const __hip_bfloat16* __restrict__ wb,
    const float* __restrict__ bho, const float* __restrict__ L,
    float* __restrict__ out) {
  int w = blockIdx.x * 4 + (threadIdx.x >> 6);
  int lane = threadIdx.x & 63;
  int rg = w / WR_NV, sl = w % WR_NV;
  int c0 = rg * (WR_MT*16);
  int v0 = sl * (WR_VT*16);
  int g = lane >> 4, c = lane & 15;
  bf16x8 bfr[WR_MT];
  float Lr[WR_MT];
  #pragma unroll
  for (int m = 0; m < WR_MT; ++m) {
    bfr[m] = *(const bf16x8*)(cb + (size_t)(c0 + m*16 + c)*KK + g*8);
    Lr[m] = L[c0 + m*16 + c];
  }
  for (int t = 0; t < WR_VT; ++t) {
    int v = v0 + t*16;
    bf16x8 af = *(const bf16x8*)(wb + (size_t)(v + c)*KK + g*8);
    f32x4 bh = *(const f32x4*)(bho + v + g*4);
    #pragma unroll
    for (int m = 0; m < WR_MT; ++m) {
      f32x4 cin = bh - Lr[m];
      f32x4 d = __builtin_amdgcn_mfma_f32_16x16x32_bf16(af, bfr[m], cin, 0, 0, 0);
      __builtin_nontemporal_store(d, (f32x4*)(out + (size_t)(c0 + m*16 + c)*VV + v + g*4));
    }
  }
}

// ------------------------------------------------------------------
extern "C" void kernel_launch(void* const* d_in, const int* in_sizes, int n_in,
                              void* d_out, int out_size, void* d_ws, size_t ws_size,
                              hipStream_t stream) {
  const int*   tok  = (const int*)d_in[0];
  const float* h0lr = (const float*)d_in[1];
  const float* h0rl = (const float*)d_in[2];
  const float* emb  = (const float*)d_in[3];
  const float* Wlr  = (const float*)d_in[4];
  const float* blr  = (const float*)d_in[5];
  const float* Wrl  = (const float*)d_in[6];
  const float* brl  = (const float*)d_in[7];
  const float* Who  = (const float*)d_in[8];
  const float* bho  = (const float*)d_in[9];
  float* out = (float*)d_out;
  float* ws  = (float*)d_ws;

  float* xp   = ws;                       // 131072 floats
  float* part = ws + 131072;              // 4096*80 = 327680 floats
  float* L    = ws + 458752;              // 4096 floats
  __hip_bfloat16* comb_bf = (__hip_bfloat16*)(ws + 462848);   // 131072 bf16
  __hip_bfloat16* who_bf  = (__hip_bfloat16*)(ws + 528384);   // 1024000 bf16

  hipLaunchKernelGGL(k_cvt, dim3((VV*KK/4 + 255)/256), dim3(256), 0, stream,
                     Who, who_bf, VV*KK/4);
  hipLaunchKernelGGL(k_xproj, dim3(512), dim3(256), 0, stream,
                     tok, emb, Wlr, blr, Wrl, brl, xp);
  hipLaunchKernelGGL(k_rnn_fused, dim3(2), dim3(512), 0, stream,
                     xp, h0lr, h0rl, Wlr, Wrl, comb_bf);
  hipLaunchKernelGGL(k_sumexp, dim3(SE_RG*SE_NV/4), dim3(256), 0, stream,
                     comb_bf, who_bf, bho, part);
  hipLaunchKernelGGL(k_merge, dim3(NROWS/256), dim3(256), 0, stream, part, L);
  hipLaunchKernelGGL(k_write, dim3(WR_RG*WR_NV/4), dim3(256), 0, stream,
                     comb_bf, who_bf, bho, L, out);
}

// Round 4
// 241.328 us; speedup vs baseline: 8.2205x; 1.1749x over previous
//
#include <hip/hip_runtime.h>
#include <hip/hip_bf16.h>
#include <math.h>

#define SS 128
#define BB 32
#define VV 32000
#define EE 32
#define HH 16
#define KK 32                 // 2*HH = GEMM K
#define NROWS (SS*BB)         // 4096
#define NSL 16                // vocab slices per row-tile
#define VT 125                // 16-wide vocab tiles per slice (16*125*16 = 32000)

typedef __attribute__((ext_vector_type(4))) float f32x4;
typedef __attribute__((ext_vector_type(8))) short bf16x8;
typedef __attribute__((ext_vector_type(4))) short s16x4;

// ------------------------------------------------------------------
// Prep: blocks 0..999 convert W_ho->bf16; blocks 1000..1511 do xproj.
// ------------------------------------------------------------------
__global__ __launch_bounds__(256) void k_prep(
    const float* __restrict__ Who, __hip_bfloat16* __restrict__ who_bf,
    const int* __restrict__ tok, const float* __restrict__ emb,
    const float* __restrict__ Wlr, const float* __restrict__ blr,
    const float* __restrict__ Wrl, const float* __restrict__ brl,
    float* __restrict__ xp) {
  if (blockIdx.x < 1000) {
    int i = blockIdx.x * 256 + threadIdx.x;      // < 256000 = VV*KK/4
    f32x4 v = ((const f32x4*)Who)[i];
    s16x4 o;
    #pragma unroll
    for (int q = 0; q < 4; ++q) {
      __hip_bfloat16 h = __float2bfloat16(v[q]);
      o[q] = *reinterpret_cast<short*>(&h);
    }
    ((s16x4*)who_bf)[i] = o;
  } else {
    int g = (blockIdx.x - 1000) * 256 + threadIdx.x;  // < 131072
    int dir = g >> 16;
    int rem = g & 65535;
    int t = rem >> 9;
    int b = (rem >> 4) & 31;
    int j = rem & 15;
    const float* W  = dir ? Wrl : Wlr;
    const float* bv = dir ? brl : blr;
    int tk = tok[t*BB + b];
    const float* er = emb + tk*EE;
    const float* wr = W + j*(EE+HH);
    float acc = bv[j];
    #pragma unroll
    for (int k = 0; k < EE; ++k) acc += er[k] * wr[k];
    xp[g] = acc;
  }
}

// ------------------------------------------------------------------
// RNN: barrier-free, cross-lane h via __shfl in 16-lane groups.
// Writes comb directly in bf16.
// ------------------------------------------------------------------
__global__ __launch_bounds__(512) void k_rnn_fused(
    const float* __restrict__ xp,
    const float* __restrict__ h0lr, const float* __restrict__ h0rl,
    const float* __restrict__ Wlr, const float* __restrict__ Wrl,
    __hip_bfloat16* __restrict__ comb_bf) {
  int dir = blockIdx.x;
  int tid = threadIdx.x;        // 0..511
  int lane = tid & 63;
  int b = tid >> 4;             // 0..31 (batch)
  int j = tid & 15;             // hidden index
  const float* W  = dir ? Wrl : Wlr;
  const float* h0 = dir ? h0rl : h0lr;
  float wh[HH];
  #pragma unroll
  for (int k = 0; k < HH; ++k) wh[k] = W[j*(EE+HH) + EE + k];
  const float* x = xp + dir * (SS*BB*HH);
  float h = h0[b*HH + j];
  if (dir == 0) comb_bf[0*(BB*KK) + b*KK + j] = __float2bfloat16(h);
  else          comb_bf[(SS-1)*(BB*KK) + b*KK + HH + j] = __float2bfloat16(h);
  int xoff  = dir ? ((SS-1)*BB*HH + tid) : tid;
  int xstep = dir ? -(BB*HH) : (BB*HH);
  float xcur = x[xoff];
  int base = lane & 48;
  for (int t = 1; t < SS; ++t) {
    float xnext = (t < SS-1) ? x[xoff + xstep] : 0.f;
    xoff += xstep;
    float acc = xcur;
    #pragma unroll
    for (int k = 0; k < HH; ++k)
      acc += wh[k] * __shfl(h, base | k);
    float e = __expf(2.f * acc);
    h = 1.f - 2.f / (e + 1.f);          // tanh(acc)
    int ci = dir ? ((SS-1-t)*(BB*KK) + b*KK + HH + j)
                 : (t*(BB*KK) + b*KK + j);
    comb_bf[ci] = __float2bfloat16(h);
    xcur = xnext;
  }
}

// ------------------------------------------------------------------
// Sum-exp: 4096 waves (1024 blocks, exactly 4/CU). wave = (row-tile rt,
// slice sl): 1 MFMA per vocab tile, 125 tiles. part[row][sl] = partial sum.
// D layout: col(l&15)=comb row, row((l>>4)*4+j)=vocab.
// ------------------------------------------------------------------
__global__ __launch_bounds__(256) void k_sumexp(
    const __hip_bfloat16* __restrict__ cb, const __hip_bfloat16* __restrict__ wb,
    const float* __restrict__ bho, float* __restrict__ part) {
  int w = blockIdx.x * 4 + (threadIdx.x >> 6);
  int lane = threadIdx.x & 63;
  int rt = w >> 4;              // 0..255
  int sl = w & 15;              // 0..15
  int v0 = sl * (VT*16);
  int g = lane >> 4, c = lane & 15;
  bf16x8 bfr = *(const bf16x8*)(cb + (size_t)(rt*16 + c)*KK + g*8);
  float s = 0.f;
  for (int t = 0; t < VT; ++t) {
    int v = v0 + t*16;
    bf16x8 af = *(const bf16x8*)(wb + (size_t)(v + c)*KK + g*8);
    f32x4 bh = *(const f32x4*)(bho + v + g*4);
    f32x4 d = __builtin_amdgcn_mfma_f32_16x16x32_bf16(af, bfr, bh, 0, 0, 0);
    s += __expf(d[0]) + __expf(d[1]) + __expf(d[2]) + __expf(d[3]);
  }
  s += __shfl_xor(s, 16);
  s += __shfl_xor(s, 32);
  if (lane < 16)
    part[(size_t)(rt*16 + lane)*NSL + sl] = s;
}

// ------------------------------------------------------------------
// Write: same 4096-wave geometry. Prologue computes L[row] from the 16
// partials (merge folded in). C-in = bho - L. Plain float4 stores.
// ------------------------------------------------------------------
__global__ __launch_bounds__(256) void k_write(
    const __hip_bfloat16* __restrict__ cb, const __hip_bfloat16* __restrict__ wb,
    const float* __restrict__ bho, const float* __restrict__ part,
    float* __restrict__ out) {
  int w = blockIdx.x * 4 + (threadIdx.x >> 6);
  int lane = threadIdx.x & 63;
  int rt = w >> 4;
  int sl = w & 15;
  int v0 = sl * (VT*16);
  int g = lane >> 4, c = lane & 15;
  size_t row = rt*16 + c;
  const f32x4* pp = (const f32x4*)(part + row*NSL);
  f32x4 p0 = pp[0], p1 = pp[1], p2 = pp[2], p3 = pp[3];
  float s = (p0[0]+p0[1]+p0[2]+p0[3]) + (p1[0]+p1[1]+p1[2]+p1[3])
          + (p2[0]+p2[1]+p2[2]+p2[3]) + (p3[0]+p3[1]+p3[2]+p3[3]);
  float Lr = logf(s);
  bf16x8 bfr = *(const bf16x8*)(cb + row*KK + g*8);
  for (int t = 0; t < VT; ++t) {
    int v = v0 + t*16;
    bf16x8 af = *(const bf16x8*)(wb + (size_t)(v + c)*KK + g*8);
    f32x4 bh = *(const f32x4*)(bho + v + g*4);
    f32x4 cin = bh - Lr;
    f32x4 d = __builtin_amdgcn_mfma_f32_16x16x32_bf16(af, bfr, cin, 0, 0, 0);
    *(f32x4*)(out + row*VV + v + g*4) = d;
  }
}

// ------------------------------------------------------------------
extern "C" void kernel_launch(void* const* d_in, const int* in_sizes, int n_in,
                              void* d_out, int out_size, void* d_ws, size_t ws_size,
                              hipStream_t stream) {
  const int*   tok  = (const int*)d_in[0];
  const float* h0lr = (const float*)d_in[1];
  const float* h0rl = (const float*)d_in[2];
  const float* emb  = (const float*)d_in[3];
  const float* Wlr  = (const float*)d_in[4];
  const float* blr  = (const float*)d_in[5];
  const float* Wrl  = (const float*)d_in[6];
  const float* brl  = (const float*)d_in[7];
  const float* Who  = (const float*)d_in[8];
  const float* bho  = (const float*)d_in[9];
  float* out = (float*)d_out;
  float* ws  = (float*)d_ws;

  float* xp   = ws;                                           // 131072 floats
  float* part = ws + 131072;                                  // 4096*16 = 65536 floats
  __hip_bfloat16* comb_bf = (__hip_bfloat16*)(ws + 196608);   // 131072 bf16
  __hip_bfloat16* who_bf  = (__hip_bfloat16*)(ws + 262144);   // 1024000 bf16

  hipLaunchKernelGGL(k_prep, dim3(1512), dim3(256), 0, stream,
                     Who, who_bf, tok, emb, Wlr, blr, Wrl, brl, xp);
  hipLaunchKernelGGL(k_rnn_fused, dim3(2), dim3(512), 0, stream,
                     xp, h0lr, h0rl, Wlr, Wrl, comb_bf);
  hipLaunchKernelGGL(k_sumexp, dim3(1024), dim3(256), 0, stream,
                     comb_bf, who_bf, bho, part);
  hipLaunchKernelGGL(k_write, dim3(1024), dim3(256), 0, stream,
                     comb_bf, who_bf, bho, part, out);
}